// Round 1
// baseline (574.876 us; speedup 1.0000x reference)
//
#include <hip/hip_runtime.h>

#define ROW_LEN 16384
#define THREADS 256
#define VPT 16          // float4 per thread (64 floats)
#define NBINS 2048
#define CAP 1024

// One block per row. Data lives in registers end-to-end; LDS only holds the
// histogram + tiny boundary list. Exact top-k-by-|x| with jax.lax.top_k
// tie-break (larger |x| first, then lower index) via composite key
// (abs_bits<<32)|~idx.
__global__ __launch_bounds__(THREADS, 4)
void topk_act_kernel(const float* __restrict__ x, const int* __restrict__ kptr,
                     float* __restrict__ out)
{
    const int t = threadIdx.x;
    const long long row = blockIdx.x;
    const float4* __restrict__ xv = (const float4*)(x + row * ROW_LEN);
    float4* __restrict__ ov = (float4*)(out + row * ROW_LEN);

    const int k = *kptr;
    if (k <= 0) {
        float4 z = make_float4(0.f, 0.f, 0.f, 0.f);
        #pragma unroll
        for (int j = 0; j < VPT; ++j) ov[j * THREADS + t] = z;
        return;
    }
    const unsigned kk = (unsigned)(k < ROW_LEN ? k : ROW_LEN);

    // ---- load row into registers (coalesced float4) ----
    float4 v[VPT];
    #pragma unroll
    for (int j = 0; j < VPT; ++j) v[j] = xv[j * THREADS + t];

    __shared__ unsigned hist[NBINS];
    __shared__ unsigned tsum[THREADS];
    __shared__ unsigned long long lst[CAP];
    __shared__ unsigned s_cnt;
    __shared__ int s_b;
    __shared__ unsigned s_g;
    __shared__ unsigned long long s_ccut;

    for (int i = t; i < NBINS; i += THREADS) hist[i] = 0u;
    if (t == 0) s_cnt = 0u;
    __syncthreads();

    // ---- phase 1: histogram of |x| over [0,4) in 1/512 bins ----
    #pragma unroll
    for (int j = 0; j < VPT; ++j) {
        const float* pf = (const float*)&v[j];
        #pragma unroll
        for (int c = 0; c < 4; ++c) {
            float a = fabsf(pf[c]);
            int bin = (int)(a * 512.0f);
            bin = bin > (NBINS - 1) ? (NBINS - 1) : bin;
            atomicAdd(&hist[bin], 1u);
        }
    }
    __syncthreads();

    // ---- phase 2: suffix scan (from top bin) to locate boundary bin b ----
    unsigned s = 0;
    #pragma unroll
    for (int i = 0; i < 8; ++i) s += hist[t * 8 + i];
    tsum[t] = s;
    __syncthreads();
    for (int off = 1; off < THREADS; off <<= 1) {
        unsigned add = (t + off < THREADS) ? tsum[t + off] : 0u;
        __syncthreads();
        tsum[t] += add;
        __syncthreads();
    }
    // tsum[t] now = inclusive suffix sum of per-thread sums
    {
        unsigned acc = (t + 1 < THREADS) ? tsum[t + 1] : 0u;  // strictly above my bins
        #pragma unroll
        for (int i = 7; i >= 0; --i) {
            int bin = t * 8 + i;
            unsigned h = hist[bin];
            if (acc < kk && acc + h >= kk) { s_b = bin; s_g = acc; }
            acc += h;
        }
    }
    __syncthreads();

    const int b = s_b;
    const unsigned g = s_g;   // count strictly above bin b (all kept)

    // ---- phase 3: collect boundary-bin elements as composite keys ----
    #pragma unroll
    for (int j = 0; j < VPT; ++j) {
        const float* pf = (const float*)&v[j];
        #pragma unroll
        for (int c = 0; c < 4; ++c) {
            float a = fabsf(pf[c]);
            int bin = (int)(a * 512.0f);
            bin = bin > (NBINS - 1) ? (NBINS - 1) : bin;
            if (bin == b) {
                unsigned p = atomicAdd(&s_cnt, 1u);
                if (p < CAP) {
                    unsigned idx = (unsigned)((j * THREADS + t) * 4 + c);
                    lst[p] = ((unsigned long long)__float_as_uint(a) << 32)
                           | (unsigned)(~idx);
                }
            }
        }
    }
    __syncthreads();

    const unsigned m = s_cnt < CAP ? s_cnt : CAP;
    unsigned r = kk - g;          // need r more from bin b; 1 <= r <= hist[b]
    if (r > m) r = m;             // safety clamp (unreachable for this input)

    // ---- phase 4: rank boundary elements; broadcast r-th-largest composite ----
    for (unsigned e = t; e < m; e += THREADS) {
        unsigned long long ce = lst[e];
        unsigned rank = 0;
        for (unsigned q = 0; q < m; ++q) rank += (lst[q] > ce) ? 1u : 0u;
        if (rank == r - 1) s_ccut = ce;   // unique: composites are distinct
    }
    __syncthreads();
    const unsigned long long ccut = s_ccut;

    // ---- phase 5: write output from registers (coalesced float4) ----
    #pragma unroll
    for (int j = 0; j < VPT; ++j) {
        const float* pf = (const float*)&v[j];
        float4 w;
        float* pw = (float*)&w;
        #pragma unroll
        for (int c = 0; c < 4; ++c) {
            float f = pf[c];
            float a = fabsf(f);
            int bin = (int)(a * 512.0f);
            bin = bin > (NBINS - 1) ? (NBINS - 1) : bin;
            bool keep;
            if (bin > b) keep = true;
            else if (bin < b) keep = false;
            else {
                unsigned idx = (unsigned)((j * THREADS + t) * 4 + c);
                unsigned long long ce = ((unsigned long long)__float_as_uint(a) << 32)
                                      | (unsigned)(~idx);
                keep = (ce >= ccut);
            }
            pw[c] = keep ? f : 0.0f;
        }
        ov[j * THREADS + t] = w;
    }
}

extern "C" void kernel_launch(void* const* d_in, const int* in_sizes, int n_in,
                              void* d_out, int out_size, void* d_ws, size_t ws_size,
                              hipStream_t stream) {
    const float* x  = (const float*)d_in[0];
    const int*   kp = (const int*)d_in[1];
    float* out = (float*)d_out;
    const int rows = out_size / ROW_LEN;   // 4096
    topk_act_kernel<<<dim3(rows), dim3(THREADS), 0, stream>>>(x, kp, out);
}

// Round 2
// 543.588 us; speedup vs baseline: 1.0576x; 1.0576x over previous
//
#include <hip/hip_runtime.h>

#define ROW_LEN 16384
#define THREADS 256
#define VPT 16          // float4 per thread (64 floats)
#define NBINS 2048
#define CAP 1024

typedef float f4v __attribute__((ext_vector_type(4)));

// One block per row. Row lives in a register array end-to-end (no address-of,
// unroll-constant indices only -> SROA keeps it in VGPRs). LDS holds only the
// histogram + boundary list. Exact top-k-by-|x| with jax.lax.top_k tie-break
// (larger |x| first, then lower index) via composite key (abs_bits<<32)|~idx.
__global__ __launch_bounds__(THREADS, 4)
void topk_act_kernel(const float* __restrict__ x, const int* __restrict__ kptr,
                     float* __restrict__ out)
{
    const int t = threadIdx.x;
    const long long row = blockIdx.x;
    const f4v* __restrict__ xv = (const f4v*)(x + row * ROW_LEN);
    f4v* __restrict__ ov = (f4v*)(out + row * ROW_LEN);

    const int k = *kptr;
    if (k <= 0) {
        f4v z = (f4v)(0.0f);
        #pragma unroll
        for (int j = 0; j < VPT; ++j)
            __builtin_nontemporal_store(z, &ov[j * THREADS + t]);
        return;
    }
    const unsigned kk = (unsigned)(k < ROW_LEN ? k : ROW_LEN);

    // ---- load row into registers (coalesced 16B, nontemporal) ----
    float va[VPT * 4];
    #pragma unroll
    for (int j = 0; j < VPT; ++j) {
        f4v tmp = __builtin_nontemporal_load(&xv[j * THREADS + t]);
        va[4 * j + 0] = tmp.x;
        va[4 * j + 1] = tmp.y;
        va[4 * j + 2] = tmp.z;
        va[4 * j + 3] = tmp.w;
    }

    __shared__ unsigned hist[NBINS];
    __shared__ unsigned tsum[THREADS];
    __shared__ unsigned long long lst[CAP];
    __shared__ unsigned s_cnt;
    __shared__ int s_b;
    __shared__ unsigned s_g;
    __shared__ unsigned long long s_ccut;

    for (int i = t; i < NBINS; i += THREADS) hist[i] = 0u;
    if (t == 0) s_cnt = 0u;
    __syncthreads();

    // ---- phase 1: histogram of |x| over [0,4) in 1/512 bins ----
    #pragma unroll
    for (int e = 0; e < VPT * 4; ++e) {
        float a = fabsf(va[e]);
        int bin = (int)(a * 512.0f);
        bin = bin > (NBINS - 1) ? (NBINS - 1) : bin;
        atomicAdd(&hist[bin], 1u);
    }
    __syncthreads();

    // ---- phase 2: suffix scan (from top bin) to locate boundary bin b ----
    unsigned s = 0;
    #pragma unroll
    for (int i = 0; i < 8; ++i) s += hist[t * 8 + i];
    tsum[t] = s;
    __syncthreads();
    for (int off = 1; off < THREADS; off <<= 1) {
        unsigned add = (t + off < THREADS) ? tsum[t + off] : 0u;
        __syncthreads();
        tsum[t] += add;
        __syncthreads();
    }
    {
        unsigned acc = (t + 1 < THREADS) ? tsum[t + 1] : 0u;  // strictly above my bins
        #pragma unroll
        for (int i = 7; i >= 0; --i) {
            int bin = t * 8 + i;
            unsigned h = hist[bin];
            if (acc < kk && acc + h >= kk) { s_b = bin; s_g = acc; }
            acc += h;
        }
    }
    __syncthreads();

    const int b = s_b;
    const unsigned g = s_g;   // count strictly above bin b (all kept)

    // ---- phase 3: collect boundary-bin elements as composite keys ----
    #pragma unroll
    for (int e = 0; e < VPT * 4; ++e) {
        float a = fabsf(va[e]);
        int bin = (int)(a * 512.0f);
        bin = bin > (NBINS - 1) ? (NBINS - 1) : bin;
        if (bin == b) {
            unsigned p = atomicAdd(&s_cnt, 1u);
            if (p < CAP) {
                unsigned idx = (unsigned)((e >> 2) * (THREADS * 4) + t * 4 + (e & 3));
                lst[p] = ((unsigned long long)__float_as_uint(a) << 32)
                       | (unsigned)(~idx);
            }
        }
    }
    __syncthreads();

    const unsigned m = s_cnt < CAP ? s_cnt : CAP;
    unsigned r = kk - g;          // need r more from bin b; 1 <= r <= hist[b]
    if (r > m) r = m;             // safety clamp

    // ---- phase 4: rank boundary elements; broadcast r-th-largest composite ----
    for (unsigned e = t; e < m; e += THREADS) {
        unsigned long long ce = lst[e];
        unsigned rank = 0;
        for (unsigned q = 0; q < m; ++q) rank += (lst[q] > ce) ? 1u : 0u;
        if (rank == r - 1) s_ccut = ce;   // unique: composites are distinct
    }
    __syncthreads();
    const unsigned long long ccut = s_ccut;

    // ---- phase 5: write output from registers (coalesced 16B, nontemporal) ----
    #pragma unroll
    for (int j = 0; j < VPT; ++j) {
        f4v w;
        #pragma unroll
        for (int c = 0; c < 4; ++c) {
            float f = va[4 * j + c];
            float a = fabsf(f);
            int bin = (int)(a * 512.0f);
            bin = bin > (NBINS - 1) ? (NBINS - 1) : bin;
            bool keep;
            if (bin > b) keep = true;
            else if (bin < b) keep = false;
            else {
                unsigned idx = (unsigned)(j * (THREADS * 4) + t * 4 + c);
                unsigned long long ce = ((unsigned long long)__float_as_uint(a) << 32)
                                      | (unsigned)(~idx);
                keep = (ce >= ccut);
            }
            w[c] = keep ? f : 0.0f;
        }
        __builtin_nontemporal_store(w, &ov[j * THREADS + t]);
    }
}

extern "C" void kernel_launch(void* const* d_in, const int* in_sizes, int n_in,
                              void* d_out, int out_size, void* d_ws, size_t ws_size,
                              hipStream_t stream) {
    const float* x  = (const float*)d_in[0];
    const int*   kp = (const int*)d_in[1];
    float* out = (float*)d_out;
    const int rows = out_size / ROW_LEN;   // 4096
    topk_act_kernel<<<dim3(rows), dim3(THREADS), 0, stream>>>(x, kp, out);
}

// Round 3
// 517.020 us; speedup vs baseline: 1.1119x; 1.0514x over previous
//
#include <hip/hip_runtime.h>

#define ROW_LEN 16384
#define THREADS 256
#define ITERS (ROW_LEN / (THREADS * 4))   // 16
#define NBINS 2048
#define CAP 1024
#define TPRE 2.0f        // pre-filter threshold; fast path only, fallback covers all data

typedef float f4v __attribute__((ext_vector_type(4)));

__device__ __forceinline__ unsigned long long make_key(float a, unsigned idx) {
    // larger |x| first, then lower index (jax.lax.top_k tie-break); keys distinct
    return ((unsigned long long)__float_as_uint(a) << 32) | (unsigned)(~idx);
}

// Suffix-scan `hist` (NBINS) and find boundary bin: count(bins > b) = g < kk <= g + hist[b].
// Requires hist finalized (barrier before call). Writes *s_b, *s_g; barrier after.
__device__ __forceinline__ void find_boundary(const unsigned* hist, unsigned kk,
                                              int* s_b, unsigned* s_g, unsigned* wtot) {
    const int t = threadIdx.x;
    const int lane = t & 63;
    const int w = t >> 6;
    unsigned s_own = 0;
    #pragma unroll
    for (int i = 0; i < 8; ++i) s_own += hist[t * 8 + i];
    unsigned acc = s_own;                       // wave-level inclusive suffix scan
    #pragma unroll
    for (int off = 1; off < 64; off <<= 1) {
        unsigned v = __shfl_down(acc, off);
        if (lane + off < 64) acc += v;
    }
    if (lane == 0) wtot[w] = acc;               // wave total
    __syncthreads();
    unsigned addw = 0;
    for (int w2 = w + 1; w2 < 4; ++w2) addw += wtot[w2];
    unsigned above = acc - s_own + addw;        // strictly above my 8-bin group
    #pragma unroll
    for (int i = 7; i >= 0; --i) {
        unsigned h = hist[t * 8 + i];
        if (above < kk && above + h >= kk) { *s_b = t * 8 + i; *s_g = above; }
        above += h;
    }
    __syncthreads();
}

__global__ __launch_bounds__(THREADS)
void topk_act_kernel(const float* __restrict__ x, const int* __restrict__ kptr,
                     float* __restrict__ out)
{
    const int t = threadIdx.x;
    const int lane = t & 63;
    const long long row = blockIdx.x;
    const f4v* __restrict__ xv = (const f4v*)(x + row * ROW_LEN);
    f4v* __restrict__ ov = (f4v*)(out + row * ROW_LEN);

    const int k = *kptr;
    if (k <= 0) {
        f4v z = (f4v)(0.0f);
        #pragma unroll
        for (int j = 0; j < ITERS; ++j)
            __builtin_nontemporal_store(z, &ov[j * THREADS + t]);
        return;
    }
    const unsigned kk = (unsigned)(k < ROW_LEN ? k : ROW_LEN);

    __shared__ unsigned hist[NBINS];
    __shared__ unsigned long long lst[CAP];
    __shared__ unsigned wtot[4];
    __shared__ unsigned s_cnt;
    __shared__ int s_b;
    __shared__ unsigned s_g;
    __shared__ unsigned long long s_ccut;

    if (t == 0) s_cnt = 0u;
    __syncthreads();

    const unsigned long long lmask_lt = (1ull << lane) - 1ull;

    // ---- sweep 1: cached read; push keys of |x| >= TPRE (wave-aggregated) ----
    for (int it = 0; it < ITERS; ++it) {
        f4v v = xv[it * THREADS + t];
        #pragma unroll
        for (int c = 0; c < 4; ++c) {
            float a = fabsf(v[c]);
            bool cond = (a >= TPRE);
            unsigned long long mk = __ballot(cond);
            unsigned cnt = (unsigned)__popcll(mk);
            if (cnt) {                                   // wave-uniform
                unsigned base = 0;
                if (lane == 0) base = atomicAdd(&s_cnt, cnt);
                base = __shfl(base, 0);
                if (cond) {
                    unsigned pos = base + (unsigned)__popcll(mk & lmask_lt);
                    if (pos < CAP) {
                        unsigned idx = (unsigned)((it * THREADS + t) * 4 + c);
                        lst[pos] = make_key(a, idx);
                    }
                }
            }
        }
    }
    __syncthreads();

    const unsigned m_all = s_cnt;
    const bool fast = (m_all >= kk && m_all <= CAP);

    if (fast) {
        // ---- refined histogram over the candidate list, bins on [TPRE, TPRE+2) ----
        for (int i = t; i < NBINS; i += THREADS) hist[i] = 0u;
        __syncthreads();
        for (unsigned e = t; e < m_all; e += THREADS) {
            float a = __uint_as_float((unsigned)(lst[e] >> 32));
            int rb = (int)((a - TPRE) * 1024.0f);
            rb = rb > (NBINS - 1) ? (NBINS - 1) : rb;
            atomicAdd(&hist[rb], 1u);
        }
        __syncthreads();
        find_boundary(hist, kk, &s_b, &s_g, wtot);
        const int bsel = s_b;
        const unsigned r = kk - s_g;         // need r-th largest within refined bin
        for (unsigned e = t; e < m_all; e += THREADS) {
            unsigned long long key = lst[e];
            float a = __uint_as_float((unsigned)(key >> 32));
            int rb = (int)((a - TPRE) * 1024.0f);
            rb = rb > (NBINS - 1) ? (NBINS - 1) : rb;
            if (rb == bsel) {
                unsigned rank = 0;
                for (unsigned q = 0; q < m_all; ++q) {
                    unsigned long long kq = lst[q];
                    float aq = __uint_as_float((unsigned)(kq >> 32));
                    int rbq = (int)((aq - TPRE) * 1024.0f);
                    rbq = rbq > (NBINS - 1) ? (NBINS - 1) : rbq;
                    rank += (rbq == bsel && kq > key) ? 1u : 0u;
                }
                if (rank == r - 1) s_ccut = key;   // unique: keys distinct
            }
        }
        __syncthreads();
    } else {
        // ---- fallback: full-range histogram over [0,4), re-scan (cached) ----
        for (int i = t; i < NBINS; i += THREADS) hist[i] = 0u;
        __syncthreads();
        for (int it = 0; it < ITERS; ++it) {
            f4v v = xv[it * THREADS + t];
            #pragma unroll
            for (int c = 0; c < 4; ++c) {
                float a = fabsf(v[c]);
                int bin = (int)(a * 512.0f);
                bin = bin > (NBINS - 1) ? (NBINS - 1) : bin;
                atomicAdd(&hist[bin], 1u);
            }
        }
        __syncthreads();
        find_boundary(hist, kk, &s_b, &s_g, wtot);
        const int b = s_b;
        const unsigned r = kk - s_g;
        if (t == 0) s_cnt = 0u;
        __syncthreads();
        for (int it = 0; it < ITERS; ++it) {
            f4v v = xv[it * THREADS + t];
            #pragma unroll
            for (int c = 0; c < 4; ++c) {
                float a = fabsf(v[c]);
                int bin = (int)(a * 512.0f);
                bin = bin > (NBINS - 1) ? (NBINS - 1) : bin;
                if (bin == b) {
                    unsigned p = atomicAdd(&s_cnt, 1u);
                    if (p < CAP) {
                        unsigned idx = (unsigned)((it * THREADS + t) * 4 + c);
                        lst[p] = make_key(a, idx);
                    }
                }
            }
        }
        __syncthreads();
        const unsigned mb = s_cnt < CAP ? s_cnt : CAP;
        for (unsigned e = t; e < mb; e += THREADS) {
            unsigned long long key = lst[e];
            unsigned rank = 0;
            for (unsigned q = 0; q < mb; ++q) rank += (lst[q] > key) ? 1u : 0u;
            if (rank == r - 1) s_ccut = key;
        }
        __syncthreads();
    }

    const unsigned long long ccut = s_ccut;

    // ---- sweep 2: re-read (L2/L3-hot), mask, nontemporal store ----
    for (int it = 0; it < ITERS; ++it) {
        f4v v = xv[it * THREADS + t];
        f4v w;
        #pragma unroll
        for (int c = 0; c < 4; ++c) {
            float f = v[c];
            unsigned idx = (unsigned)((it * THREADS + t) * 4 + c);
            unsigned long long key = make_key(fabsf(f), idx);
            w[c] = (key >= ccut) ? f : 0.0f;
        }
        __builtin_nontemporal_store(w, &ov[it * THREADS + t]);
    }
}

extern "C" void kernel_launch(void* const* d_in, const int* in_sizes, int n_in,
                              void* d_out, int out_size, void* d_ws, size_t ws_size,
                              hipStream_t stream) {
    const float* x  = (const float*)d_in[0];
    const int*   kp = (const int*)d_in[1];
    float* out = (float*)d_out;
    const int rows = out_size / ROW_LEN;   // 4096
    topk_act_kernel<<<dim3(rows), dim3(THREADS), 0, stream>>>(x, kp, out);
}

// Round 4
// 462.511 us; speedup vs baseline: 1.2429x; 1.1179x over previous
//
#include <hip/hip_runtime.h>

#define ROW_LEN 16384
#define THREADS 256
#define ITERS (ROW_LEN / (THREADS * 4))   // 16
#define NBINS 2048
#define CAP 1024
#define MBCAP 128
#define TPRE 2.5f        // pre-filter; E[count]≈204/row for N(0,1). Fallback covers all data.

typedef float f4v __attribute__((ext_vector_type(4)));

// Composite key: larger |x| first, then lower index (jax.lax.top_k tie-break).
__device__ __forceinline__ unsigned long long make_key(unsigned abits, unsigned idx) {
    return ((unsigned long long)abits << 32) | (unsigned)(~idx);
}

// Find boundary bin b: count(bins>b)=g < kk <= g+hist[b]. Barrier before+after inside.
__device__ __forceinline__ void find_boundary(const unsigned* hist, unsigned kk,
                                              int* s_b, unsigned* s_g, unsigned* wtot) {
    const int t = threadIdx.x;
    const int lane = t & 63;
    const int w = t >> 6;
    unsigned s_own = 0;
    #pragma unroll
    for (int i = 0; i < 8; ++i) s_own += hist[t * 8 + i];
    unsigned acc = s_own;                       // wave inclusive suffix scan
    #pragma unroll
    for (int off = 1; off < 64; off <<= 1) {
        unsigned v = __shfl_down(acc, off);
        if (lane + off < 64) acc += v;
    }
    if (lane == 0) wtot[w] = acc;
    __syncthreads();
    unsigned addw = 0;
    #pragma unroll
    for (int w2 = 0; w2 < THREADS / 64; ++w2) if (w2 > w) addw += wtot[w2];
    unsigned above = acc - s_own + addw;        // strictly above my 8-bin group
    #pragma unroll
    for (int i = 7; i >= 0; --i) {
        unsigned h = hist[t * 8 + i];
        if (above < kk && above + h >= kk) { *s_b = t * 8 + i; *s_g = above; }
        above += h;
    }
    __syncthreads();
}

__global__ __launch_bounds__(THREADS)
void topk_act_kernel(const float* __restrict__ x, const int* __restrict__ kptr,
                     float* __restrict__ out)
{
    const int t = threadIdx.x;
    const long long row = blockIdx.x;
    const f4v* __restrict__ xv = (const f4v*)(x + row * ROW_LEN);
    f4v* __restrict__ ov = (f4v*)(out + row * ROW_LEN);

    const int k = *kptr;
    if (k <= 0) {
        f4v z = (f4v)(0.0f);
        #pragma unroll
        for (int j = 0; j < ITERS; ++j)
            __builtin_nontemporal_store(z, &ov[j * THREADS + t]);
        return;
    }
    const unsigned kk = (unsigned)(k < ROW_LEN ? k : ROW_LEN);

    __shared__ unsigned hist[NBINS];
    __shared__ unsigned long long lst[CAP];
    __shared__ unsigned long long lst2[MBCAP];
    __shared__ unsigned wtot[THREADS / 64];
    __shared__ unsigned s_cnt, s_cnt2;
    __shared__ int s_b;
    __shared__ unsigned s_g;
    __shared__ unsigned long long s_ccut;

    if (t == 0) { s_cnt = 0u; s_cnt2 = 0u; }
    __syncthreads();

    // ---- sweep 1: stream row (populates L2); cheap divergent push of rare candidates ----
    const unsigned abs_pre = __float_as_uint(TPRE);
    for (int it = 0; it < ITERS; ++it) {
        f4v v = xv[it * THREADS + t];
        #pragma unroll
        for (int c = 0; c < 4; ++c) {
            unsigned ab = __float_as_uint(v[c]) & 0x7fffffffu;
            if (ab >= abs_pre) {                      // ~1.2% of elements
                unsigned p = atomicAdd(&s_cnt, 1u);
                if (p < CAP) {
                    unsigned idx = (unsigned)((it * THREADS + t) * 4 + c);
                    lst[p] = make_key(ab, idx);
                }
            }
        }
    }
    __syncthreads();

    const unsigned m_all = s_cnt;

    if (m_all >= kk && m_all <= CAP) {
        // ---- fast path: kk-th largest key lies inside lst ----
        for (int i = t; i < NBINS; i += THREADS) hist[i] = 0u;
        __syncthreads();
        for (unsigned e = t; e < m_all; e += THREADS) {
            float a = __uint_as_float((unsigned)(lst[e] >> 32));
            int rb = (int)((a - TPRE) * 1024.0f);       // bins over [2.5, 4.5)
            rb = rb > (NBINS - 1) ? (NBINS - 1) : rb;
            atomicAdd(&hist[rb], 1u);
        }
        __syncthreads();
        find_boundary(hist, kk, &s_b, &s_g, wtot);
        const int bsel = s_b;
        const unsigned r = kk - s_g;                    // r-th largest within bin bsel
        for (unsigned e = t; e < m_all; e += THREADS) { // gather boundary bin (tiny)
            unsigned long long key = lst[e];
            float a = __uint_as_float((unsigned)(key >> 32));
            int rb = (int)((a - TPRE) * 1024.0f);
            rb = rb > (NBINS - 1) ? (NBINS - 1) : rb;
            if (rb == bsel) {
                unsigned p = atomicAdd(&s_cnt2, 1u);
                if (p < MBCAP) lst2[p] = key;
            }
        }
        __syncthreads();
        const unsigned mb = s_cnt2;
        if (mb <= MBCAP) {
            for (unsigned e = t; e < mb; e += THREADS) {
                unsigned long long ce = lst2[e];
                unsigned rank = 0;
                for (unsigned q = 0; q < mb; ++q) rank += (lst2[q] > ce) ? 1u : 0u;
                if (rank == r - 1) s_ccut = ce;          // unique: keys distinct
            }
        } else {                                         // overflow: rank vs full list
            for (unsigned e = t; e < m_all; e += THREADS) {
                unsigned long long ce = lst[e];
                float a = __uint_as_float((unsigned)(ce >> 32));
                int rb = (int)((a - TPRE) * 1024.0f);
                rb = rb > (NBINS - 1) ? (NBINS - 1) : rb;
                if (rb == bsel) {
                    unsigned rank = 0;
                    for (unsigned q = 0; q < m_all; ++q) {
                        unsigned long long kq = lst[q];
                        float aq = __uint_as_float((unsigned)(kq >> 32));
                        int rbq = (int)((aq - TPRE) * 1024.0f);
                        rbq = rbq > (NBINS - 1) ? (NBINS - 1) : rbq;
                        rank += (rbq == bsel && kq > ce) ? 1u : 0u;
                    }
                    if (rank == r - 1) s_ccut = ce;
                }
            }
        }
        __syncthreads();
    } else {
        // ---- fallback (never taken for N(0,1) data; guarantees correctness) ----
        for (int i = t; i < NBINS; i += THREADS) hist[i] = 0u;
        if (t == 0) s_cnt = 0u;
        __syncthreads();
        for (int it = 0; it < ITERS; ++it) {
            f4v v = xv[it * THREADS + t];
            #pragma unroll
            for (int c = 0; c < 4; ++c) {
                float a = fabsf(v[c]);
                int bin = (int)(a * 256.0f);             // bins over [0, 8)
                bin = bin > (NBINS - 1) ? (NBINS - 1) : bin;
                atomicAdd(&hist[bin], 1u);
            }
        }
        __syncthreads();
        find_boundary(hist, kk, &s_b, &s_g, wtot);
        const int b = s_b;
        unsigned r = kk - s_g;
        for (int it = 0; it < ITERS; ++it) {             // gather bin-b keys
            f4v v = xv[it * THREADS + t];
            #pragma unroll
            for (int c = 0; c < 4; ++c) {
                unsigned ab = __float_as_uint(v[c]) & 0x7fffffffu;
                float a = __uint_as_float(ab);
                int bin = (int)(a * 256.0f);
                bin = bin > (NBINS - 1) ? (NBINS - 1) : bin;
                if (bin == b) {
                    unsigned p = atomicAdd(&s_cnt, 1u);
                    if (p < CAP) {
                        unsigned idx = (unsigned)((it * THREADS + t) * 4 + c);
                        lst[p] = make_key(ab, idx);
                    }
                }
            }
        }
        __syncthreads();
        const unsigned mbf = s_cnt < CAP ? s_cnt : CAP;
        if (r > mbf) r = mbf;
        for (unsigned e = t; e < mbf; e += THREADS) {
            unsigned long long ce = lst[e];
            unsigned rank = 0;
            for (unsigned q = 0; q < mbf; ++q) rank += (lst[q] > ce) ? 1u : 0u;
            if (rank == r - 1) s_ccut = ce;
        }
        __syncthreads();
    }

    const unsigned long long cc = s_ccut;
    const unsigned cut_hi = (unsigned)(cc >> 32);
    const unsigned cut_lo = (unsigned)cc;                // == ~cut_idx

    // ---- sweep 2: re-read (L2-hot), mask with uint abs-bit compare, stream out ----
    for (int it = 0; it < ITERS; ++it) {
        f4v v = xv[it * THREADS + t];
        f4v w;
        #pragma unroll
        for (int c = 0; c < 4; ++c) {
            unsigned ab = __float_as_uint(v[c]) & 0x7fffffffu;
            unsigned idx = (unsigned)((it * THREADS + t) * 4 + c);
            bool keep = (ab > cut_hi) | ((ab == cut_hi) & (~idx >= cut_lo));
            w[c] = keep ? v[c] : 0.0f;
        }
        __builtin_nontemporal_store(w, &ov[it * THREADS + t]);
    }
}

extern "C" void kernel_launch(void* const* d_in, const int* in_sizes, int n_in,
                              void* d_out, int out_size, void* d_ws, size_t ws_size,
                              hipStream_t stream) {
    const float* x  = (const float*)d_in[0];
    const int*   kp = (const int*)d_in[1];
    float* out = (float*)d_out;
    const int rows = out_size / ROW_LEN;   // 4096
    topk_act_kernel<<<dim3(rows), dim3(THREADS), 0, stream>>>(x, kp, out);
}